// Round 3
// baseline (1350.044 us; speedup 1.0000x reference)
//
#include <hip/hip_runtime.h>

#define NC 512   // N_CLUSTERS

// ===========================================================================
// Pre-pass: pack LUTs to u16; transpose conv/fc LUTs so build gathers have a
// wave-uniform row (lutT[w][s], 1KB row => <=16 lines per 64-lane gather).
// ===========================================================================
__global__ __launch_bounds__(256) void k_transpose_pack(
    const int* __restrict__ src, unsigned short* __restrict__ dst)  // dst[w][s]=src[s][w]
{
    __shared__ unsigned short tile[64][65];
    int tx = blockIdx.x % 8, ty = blockIdx.x / 8;       // 8x8 grid of 64x64 tiles
    int lane = threadIdx.x & 63, grp = threadIdx.x >> 6;
    for (int r = grp * 16; r < grp * 16 + 16; ++r)
        tile[r][lane] = (unsigned short)src[(ty * 64 + r) * NC + tx * 64 + lane];
    __syncthreads();
    for (int r = grp * 16; r < grp * 16 + 16; ++r)
        dst[(tx * 64 + r) * NC + ty * 64 + lane] = tile[lane][r];
}

__global__ __launch_bounds__(256) void k_pack_add(
    const int* __restrict__ src, unsigned short* __restrict__ dst)
{
    int base = blockIdx.x * 1024 + threadIdx.x;
    for (int i = 0; i < 4; ++i) dst[base + i * 256] = (unsigned short)src[base + i * 256];
}

// ===========================================================================
// Stage 1: discretize -> u16 symbols.
// ===========================================================================
__global__ __launch_bounds__(256) void k_discretize(
    const float* __restrict__ x, const float* __restrict__ cent,
    unsigned short* __restrict__ out)
{
    __shared__ float c[NC];
    int tid = threadIdx.x;
    for (int i = tid; i < NC; i += 256) c[i] = cent[i];
    __syncthreads();
    int id = blockIdx.x * 256 + tid;   // 131072 exact
    float px = x[id];
    float best = fabsf(px - c[0]);
    int bi = 0;
    for (int k = 1; k < NC; ++k) {
        float d = fabsf(px - c[k]);
        if (d < best) { best = d; bi = k; }
    }
    out[id] = (unsigned short)bi;
}

// ===========================================================================
// Register-window pop-min scanner (verified R2). Per-lane 512-bin u8 multiset
// in LDS; 32-byte window cached in 8 VGPRs + nonzero mask.
// ===========================================================================
struct ScanU8 {
    unsigned char* base;
    uint32_t w[8];
    uint32_t mask;
    int chunk;

    static __device__ inline uint32_t nz4(uint32_t x) {
        uint32_t y = (x & 0x7F7F7F7Fu) + 0x7F7F7F7Fu;
        y = (y | x) & 0x80808080u;
        return (y * 0x00204081u) >> 28;
    }
    __device__ inline void init(unsigned char* b) { base = b; mask = 0; chunk = -1; }
    __device__ inline void load() {
        const uint4* p = (const uint4*)(base + chunk * 32);
        uint4 a = p[0], b2 = p[1];
        w[0]=a.x; w[1]=a.y; w[2]=a.z; w[3]=a.w;
        w[4]=b2.x; w[5]=b2.y; w[6]=b2.z; w[7]=b2.w;
        mask =  nz4(w[0])        | (nz4(w[1]) << 4)  | (nz4(w[2]) << 8)  | (nz4(w[3]) << 12)
             | (nz4(w[4]) << 16) | (nz4(w[5]) << 20) | (nz4(w[6]) << 24) | (nz4(w[7]) << 28);
    }
    __device__ inline void ensure() { while (mask == 0) { ++chunk; load(); } }
    __device__ inline int  peek()   { ensure(); return chunk * 32 + (int)__builtin_ctz(mask); }
    __device__ inline void consume_min() {
        int k = (int)__builtin_ctz(mask);
        int dw = k >> 2, sh = (k & 3) << 3;
        uint32_t cnt = 0;
#pragma unroll
        for (int i = 0; i < 8; ++i) if (i == dw) { cnt = (w[i] >> sh) & 0xFFu; w[i] -= (1u << sh); }
        if (cnt == 1) mask &= ~(1u << k);
    }
    __device__ inline int pop() { int v = peek(); consume_min(); return v; }
    __device__ inline void insert(int v) {
        int rel = v - chunk * 32;
        if (rel < 32) {
            int dw = rel >> 2, sh = (rel & 3) << 3;
#pragma unroll
            for (int i = 0; i < 8; ++i) if (i == dw) w[i] += (1u << sh);
            mask |= (1u << rel);
        } else {
            base[v] = (unsigned char)(base[v] + 1);
        }
    }
};

// ===========================================================================
// Symbolic conv (k=5, s=2), _conv_reduce semantics (verified R1/R2).
// Block = (co, 64 spatial positions): co wave-uniform => uniform-row builds.
// Input tile staged in LDS as u16. OUT_T: write transposed (k,b) for fc1.
// ===========================================================================
template<int CIN, int CO, int IH, int IW, int OH, int OW, int MAX_IMGS, bool OUT_T>
__global__ __launch_bounds__(64) void k_conv(
    const unsigned short* __restrict__ in_sym,  // (B, IH, IW, CIN) u16
    const int* __restrict__ wsym,               // (25*CIN, CO)
    const unsigned short* __restrict__ convT,   // (NC, NC) u16, [w][s]
    const unsigned short* __restrict__ add16,   // (NC, NC) u16
    const int* __restrict__ bias_lut,           // (NC, CO)
    const int* __restrict__ relu_lut,           // (NC,)
    unsigned short* __restrict__ out)
{
    constexpr int N   = 25 * CIN;
    constexpr int IMG = IH * IW * CIN;
    constexpr int PPI = OH * OW;               // positions per image
    constexpr int BPC = (128 * PPI) / 64;      // blocks per co
    __shared__ __align__(16) unsigned char bins[64 * NC];          // 32 KB
    __shared__ __align__(16) unsigned short tile[MAX_IMGS * IMG];
    int tid = threadIdx.x;

    uint32_t* bz = (uint32_t*)bins;
    for (int i = 0; i < 128; ++i) bz[i * 64 + tid] = 0u;

    int posg = blockIdx.x % BPC;
    int co   = blockIdx.x / BPC;               // wave-uniform
    int pos  = posg * 64 + tid;
    int b  = pos / PPI;
    int yx = pos % PPI;
    int oy = yx / OW, ox = yx % OW;

    int bfirst = (posg * 64) / PPI;
    int bbase = bfirst > (128 - MAX_IMGS) ? (128 - MAX_IMGS) : bfirst;
    constexpr int NW = MAX_IMGS * IMG / 2;     // u32 words to stage
    const uint32_t* src = (const uint32_t*)(in_sym + bbase * IMG);
    uint32_t* tdst = (uint32_t*)tile;
    for (int i = tid; i < NW; i += 64) tdst[i] = src[i];
    __syncthreads();

    const unsigned short* mytile = tile + (b - bbase) * IMG;
    unsigned char* mybins = bins + tid * NC;
    for (int n = 0; n < N; ++n) {
        int i   = n / (5 * CIN);
        int rem = n % (5 * CIN);
        int j   = rem / CIN;
        int c   = rem % CIN;
        int s = mytile[((oy * 2 + i) * IW + (ox * 2 + j)) * CIN + c];
        int w = wsym[n * CO + co];                       // uniform scalar
        int g = convT[w * NC + s];                       // uniform row, <=16 lines
        mybins[g] = (unsigned char)(mybins[g] + 1);
    }

    ScanU8 sc; sc.init(mybins);
    int t = sc.pop();
    for (int j = 1; j < N; ++j) {
        int x = sc.pop();
        int t2 = add16[x * NC + t];
        if (j < N - 2) {
            int y = sc.peek();
            if (t2 > y) { sc.consume_min(); sc.insert(t2); t = y; }
            else t = t2;
        } else t = t2;
    }
    int r = relu_lut[bias_lut[t * CO + co]];
    if (OUT_T) out[(co * PPI + yx) * 128 + b] = (unsigned short)r;  // (k, b) for fc1
    else       out[pos * CO + co] = (unsigned short)r;              // (b,OH,OW,CO)
}

// ===========================================================================
// Symbolic FC, _fc_reduce = ascending pops. Block = (m, 64 batch rows):
// m wave-uniform => uniform-row builds; input (k,b) layout => coalesced reads.
// WINDOW: stream add16 rows through a 32KB LDS window (pops are monotone).
// ===========================================================================
template<int M, int K, bool WINDOW>
__global__ __launch_bounds__(64) void k_fc(
    const unsigned short* __restrict__ inT,    // (K, 128) u16
    const int* __restrict__ wsym,              // (M, K)
    const unsigned short* __restrict__ fcT,    // (NC, NC) u16, [w][x]
    const unsigned short* __restrict__ add16,  // (NC, NC) u16
    const int* __restrict__ bias_lut,          // (NC, M)
    const int* __restrict__ relu_lut,
    unsigned short* __restrict__ outT)         // (M, 128)
{
    __shared__ __align__(16) unsigned char bins[64 * NC];            // 32 KB
    __shared__ __align__(16) unsigned short win[WINDOW ? 32 * NC : 8]; // 32 KB
    int tid = threadIdx.x;

    uint32_t* bz = (uint32_t*)bins;
    for (int i = 0; i < 128; ++i) bz[i * 64 + tid] = 0u;
    __syncthreads();   // bins are lane-private, but keep zero globally ordered

    int m = blockIdx.x >> 1;                   // wave-uniform
    int b = (blockIdx.x & 1) * 64 + tid;

    unsigned char* mybins = bins + tid * NC;
    for (int k = 0; k < K; ++k) {
        int x = inT[k * 128 + b];              // coalesced
        int w = wsym[m * K + k];               // uniform scalar
        int g = fcT[w * NC + x];               // uniform row
        mybins[g] = (unsigned char)(mybins[g] + 1);
    }

    ScanU8 sc; sc.init(mybins);
    int t = sc.pop();
    if (WINDOW) {
        int remaining = K - 1;
        int x = sc.pop();
        bool have = true;
        for (int r0 = 0; r0 < NC; r0 += 32) {
            const uint4* gsrc = (const uint4*)(add16 + r0 * NC);
            uint4* wdst = (uint4*)win;
            for (int i = 0; i < 32; ++i) wdst[i * 64 + tid] = gsrc[i * 64 + tid];
            __syncthreads();
            while (have && x < r0 + 32) {
                t = win[(x - r0) * NC + t];
                if (--remaining > 0) x = sc.pop(); else have = false;
            }
            __syncthreads();
        }
    } else {
        for (int s = 1; s < K; ++s) t = add16[sc.pop() * NC + t];
    }
    outT[m * 128 + b] = (unsigned short)relu_lut[bias_lut[t * M + m]];
}

// ===========================================================================
// Head: feats = centroid[sym], logits = feats @ W^T + b, softmax.
// ===========================================================================
__global__ __launch_bounds__(64) void k_head(
    const unsigned short* __restrict__ f2T,    // (84, 128)
    const float* __restrict__ cent,            // (NC,)
    const float* __restrict__ w,               // (10, 84)
    const float* __restrict__ bias,            // (10,)
    float* __restrict__ out)                   // (128, 10)
{
    int b = blockIdx.x * 64 + threadIdx.x;
    float acc[10];
#pragma unroll
    for (int o = 0; o < 10; ++o) acc[o] = bias[o];
    for (int k = 0; k < 84; ++k) {
        float f = cent[f2T[k * 128 + b]];      // coalesced
#pragma unroll
        for (int o = 0; o < 10; ++o) acc[o] += f * w[o * 84 + k];
    }
    float mx = acc[0];
#pragma unroll
    for (int o = 1; o < 10; ++o) mx = fmaxf(mx, acc[o]);
    float s = 0.f;
#pragma unroll
    for (int o = 0; o < 10; ++o) { acc[o] = expf(acc[o] - mx); s += acc[o]; }
    float inv = 1.f / s;
#pragma unroll
    for (int o = 0; o < 10; ++o) out[b * 10 + o] = acc[o] * inv;
}

// ===========================================================================
extern "C" void kernel_launch(void* const* d_in, const int* in_sizes, int n_in,
                              void* d_out, int out_size, void* d_ws, size_t ws_size,
                              hipStream_t stream)
{
    const float* x_bat  = (const float*)d_in[0];
    const float* cent   = (const float*)d_in[1];
    const int* conv_lut = (const int*)d_in[2];
    const int* fc_lut   = (const int*)d_in[3];
    const int* add_lut  = (const int*)d_in[4];
    const int* relu_lut = (const int*)d_in[5];
    const int* c1_bias  = (const int*)d_in[6];
    const int* c2_bias  = (const int*)d_in[7];
    const int* f1_bias  = (const int*)d_in[8];
    const int* f2_bias  = (const int*)d_in[9];
    const int* c1f      = (const int*)d_in[10];
    const int* c2f      = (const int*)d_in[11];
    const int* f1f      = (const int*)d_in[12];
    const int* f2f      = (const int*)d_in[13];
    const float* fc3_w  = (const float*)d_in[14];
    const float* fc3_b  = (const float*)d_in[15];
    float* out = (float*)d_out;

    char* ws = (char*)d_ws;
    unsigned short* convT = (unsigned short*)(ws);            // 512 KB
    unsigned short* fcT   = (unsigned short*)(ws + 524288);   // 512 KB
    unsigned short* add16 = (unsigned short*)(ws + 1048576);  // 512 KB
    unsigned short* sym0  = (unsigned short*)(ws + 1572864);  // 256 KB
    unsigned short* c1o   = (unsigned short*)(ws + 1835008);  // 294 KB (b,14,14,6)
    unsigned short* c2oT  = (unsigned short*)(ws + 2136064);  // 100 KB (400,128)
    unsigned short* f1oT  = (unsigned short*)(ws + 2238464);  //  30 KB (120,128)
    unsigned short* f2oT  = (unsigned short*)(ws + 2269184);  //  21 KB (84,128)

    k_transpose_pack<<<64, 256, 0, stream>>>(conv_lut, convT);
    k_transpose_pack<<<64, 256, 0, stream>>>(fc_lut, fcT);
    k_pack_add<<<256, 256, 0, stream>>>(add_lut, add16);
    k_discretize<<<512, 256, 0, stream>>>(x_bat, cent, sym0);

    // conv1: 6 co x 392 pos-groups = 2352 blocks
    k_conv<1, 6, 32, 32, 14, 14, 2, false><<<2352, 64, 0, stream>>>(
        sym0, c1f, convT, add16, c1_bias, relu_lut, c1o);
    // conv2: 16 co x 50 pos-groups = 800 blocks, writes (k,b) for fc1
    k_conv<6, 16, 14, 14, 5, 5, 4, true><<<800, 64, 0, stream>>>(
        c1o, c2f, convT, add16, c2_bias, relu_lut, c2oT);
    // fc1: 120 m x 2 halves, windowed fold
    k_fc<120, 400, true><<<240, 64, 0, stream>>>(
        c2oT, f1f, fcT, add16, f1_bias, relu_lut, f1oT);
    // fc2: 84 m x 2 halves, direct fold
    k_fc<84, 120, false><<<168, 64, 0, stream>>>(
        f1oT, f2f, fcT, add16, f2_bias, relu_lut, f2oT);
    k_head<<<2, 64, 0, stream>>>(f2oT, cent, fc3_w, fc3_b, out);
}